// Round 12
// baseline (238.005 us; speedup 1.0000x reference)
//
#include <hip/hip_runtime.h>
#include <hip/hip_bf16.h>
#include <math.h>

typedef __bf16 bf16x2 __attribute__((ext_vector_type(2)));
typedef __bf16 bf16x4 __attribute__((ext_vector_type(4)));
typedef __bf16 bf16x8 __attribute__((ext_vector_type(8)));
typedef float f32x4 __attribute__((ext_vector_type(4)));
typedef float f32x16 __attribute__((ext_vector_type(16)));

#define MFMA16(a, b, c) __builtin_amdgcn_mfma_f32_16x16x32_bf16(a, b, c, 0, 0, 0)
#define MFMA32(a, b, c) __builtin_amdgcn_mfma_f32_32x32x16_bf16(a, b, c, 0, 0, 0)
#define QSCALE 0.1803368801111204f  // 0.125 * log2(e): folded into W's Q-columns

// async global->LDS, 16B/lane, dest = wave-uniform base + lane*16
__device__ __forceinline__ void gload_lds16(const __bf16* g, __bf16* l) {
  __builtin_amdgcn_global_load_lds((const __attribute__((address_space(1))) void*)g,
                                   (__attribute__((address_space(3))) void*)l,
                                   16, 0, 0);
}

// ---------------------------------------------------------------------------
// Kernel 0: convert X fp32 -> bf16
// ---------------------------------------------------------------------------
__global__ __launch_bounds__(256) void convert_x(const float* __restrict__ in,
                                                 __bf16* __restrict__ out) {
  int i = blockIdx.x * 256 + threadIdx.x;
  float4 v = ((const float4*)in)[i];
  bf16x4 o = {(__bf16)v.x, (__bf16)v.y, (__bf16)v.z, (__bf16)v.w};
  *(bf16x4*)&out[i * 4] = o;
}

// ---------------------------------------------------------------------------
// Kernel 1: transpose+convert W fp32 [1024,3072] -> Wt bf16 [3072,1024].
//   Q output-features (bx<16) pre-scaled by 0.125*log2(e).
// ---------------------------------------------------------------------------
__global__ __launch_bounds__(256) void transpose_w(const float* __restrict__ W,
                                                   __bf16* __restrict__ Wt) {
  __shared__ __bf16 tile[64][65];
  const int bx = blockIdx.x;
  const int by = blockIdx.y;
  const int t = threadIdx.x;
  const int lr = t >> 6;
  const int lc = t & 63;
  const float sc = (bx < 16) ? QSCALE : 1.0f;  // block-uniform
#pragma unroll
  for (int i = 0; i < 16; ++i) {
    int r = lr + i * 4;
    tile[r][lc] = (__bf16)(W[(size_t)(by * 64 + r) * 3072 + bx * 64 + lc] * sc);
  }
  __syncthreads();
#pragma unroll
  for (int i = 0; i < 16; ++i) {
    int r = lr + i * 4;
    Wt[(size_t)(bx * 64 + r) * 1024 + by * 64 + lc] = tile[lc][r];
  }
}

// ---------------------------------------------------------------------------
// Kernel 2: QKV = X @ W. R8/R11-verified structure (128x128 tile, BK=32,
//   global_load_lds w=16, 256 thr, 36KB LDS, 4-block TLP) + XCD 4x2 remap.
//   Unchanged from R11 (235.5 us config).
// ---------------------------------------------------------------------------
__global__ __launch_bounds__(256) void gemm_qkv(const __bf16* __restrict__ X,
                                                const __bf16* __restrict__ Wt,
                                                __bf16* __restrict__ QK,
                                                __bf16* __restrict__ Vt) {
  __shared__ __bf16 As[128 * 32];
  __shared__ __bf16 Bs[128 * 32];
  const int t = threadIdx.x;
  const int lane = t & 63;
  const int wave = t >> 6;
  const int quad = lane >> 4;
  const int l16 = lane & 15;

  // ---- XCD-aware 4x2 tiling remap (T1) ----
  const int flat = blockIdx.x + blockIdx.y * 24;
  const int xcd = flat & 7;
  const int i = flat >> 3;       // 0..191 within XCD
  const int mg = xcd >> 1;       // 4 m-groups
  const int ng = xcd & 1;        // 2 n-groups
  const int nb = i >> 4;         // 0..11, outer (B panel hot across 16 mb)
  const int mb = i & 15;         // 0..15, inner
  const int n0 = (ng * 12 + nb) * 128;
  const int m0 = (mg * 16 + mb) * 128;

  const int wm = (wave & 1) * 64;
  const int wn = (wave >> 1) * 64;

  const __bf16* Ag = &X[(size_t)(m0 + wave * 16 + (lane >> 2)) * 1024 + (lane & 3) * 8];
  const __bf16* Bg = &Wt[(size_t)(n0 + wave * 16 + (lane >> 2)) * 1024 + (lane & 3) * 8];
  __bf16* As0 = &As[wave * 512];
  __bf16* As1 = &As[2048 + wave * 512];
  __bf16* Bs0 = &Bs[wave * 512];
  __bf16* Bs1 = &Bs[2048 + wave * 512];

  f32x4 acc[4][4] = {};

  for (int k0 = 0; k0 < 1024; k0 += 32) {
    gload_lds16(Ag + k0, As0);
    gload_lds16(Ag + (size_t)64 * 1024 + k0, As1);
    gload_lds16(Bg + k0, Bs0);
    gload_lds16(Bg + (size_t)64 * 1024 + k0, Bs1);
    __syncthreads();

    bf16x8 af[4], bf[4];
#pragma unroll
    for (int mi = 0; mi < 4; ++mi)
      af[mi] = *(const bf16x8*)&As[(wm + mi * 16 + l16) * 32 + quad * 8];
#pragma unroll
    for (int ni = 0; ni < 4; ++ni)
      bf[ni] = *(const bf16x8*)&Bs[(wn + ni * 16 + l16) * 32 + quad * 8];
#pragma unroll
    for (int mi = 0; mi < 4; ++mi)
#pragma unroll
      for (int ni = 0; ni < 4; ++ni)
        acc[mi][ni] = MFMA16(af[mi], bf[ni], acc[mi][ni]);
    __syncthreads();
  }

  if (n0 < 2048) {
    // Q/K epilogue: row-major QK, stride 2048
#pragma unroll
    for (int mi = 0; mi < 4; ++mi)
#pragma unroll
      for (int ni = 0; ni < 4; ++ni)
#pragma unroll
        for (int r = 0; r < 4; ++r) {
          int row = m0 + wm + mi * 16 + quad * 4 + r;
          int col = n0 + wn + ni * 16 + l16;
          QK[(size_t)row * 2048 + col] = (__bf16)acc[mi][ni][r];
        }
  } else {
    // V epilogue: fused transpose into Vt[bh][d][key]; 4 consecutive keys
#pragma unroll
    for (int mi = 0; mi < 4; ++mi)
#pragma unroll
      for (int ni = 0; ni < 4; ++ni) {
        int v = n0 + wn + ni * 16 + l16 - 2048;
        int hh = v >> 6, d = v & 63;
        int row0 = m0 + wm + mi * 16 + quad * 4;
        int bb = row0 >> 11, key = row0 & 2047;
        bf16x4 pk = {(__bf16)acc[mi][ni][0], (__bf16)acc[mi][ni][1],
                     (__bf16)acc[mi][ni][2], (__bf16)acc[mi][ni][3]};
        *(bf16x4*)&Vt[((size_t)(bb * 16 + hh) * 64 + d) * 2048 + key] = pk;
      }
  }
}

// ---------------------------------------------------------------------------
// Kernel 3: flash attention — gload_lds staging + XOR-swizzle + 1-barrier
//   double-buffer pipeline. (VALUBusy 55% was dominated by reg-staging
//   machinery; Common-mistake #1 + rule #21 + m201.)
//   LDS tiles are UNPADDED [64 rows][64 elems=8 chunks x 16B]. Swizzle:
//   LDS[r][ch] holds GLOBAL[src_row(r)][ch ^ (r&7)]; reads XOR (l31&7).
//   For K, src_row(r) = prow(r) (bits 2<->3, involution) -> identical Ks
//   semantics to the R8-verified kernel (exp2 outputs land in PV A-frag
//   order). DMA dest is linear (wave base + lane*16); the permutation +
//   swizzle live entirely in the per-lane GLOBAL source address.
//   Pipeline per round: [issue 4 gload_lds for tile it+1 into buf^1] ->
//   compute tile it from buf (loads hidden under 16 MFMA + 32 exp2) ->
//   vmcnt(0) -> barrier. ONE barrier/round. Buffers: issue writes buf^1,
//   compute reads buf; round it+1's issue (writes buf) comes after the
//   barrier that retires round it's reads of buf. 32 KB LDS.
//   Fixed-max softmax; denominator = per-lane sum + shfl_xor(32).
//   T1 XCD remap unchanged (FETCH 139->24.6 MB verified).
// ---------------------------------------------------------------------------
__global__ __launch_bounds__(256) void attn(const __bf16* __restrict__ QK,
                                            const __bf16* __restrict__ Vt,
                                            float* __restrict__ Out) {
  const int t = threadIdx.x;
  const int lane = t & 63;
  const int wave = t >> 6;
  const int l31 = lane & 31;
  const int half = lane >> 5;

  // ---- XCD-aware remap (T1) ----
  const int flat = blockIdx.x + (blockIdx.y << 4) + (blockIdx.z << 8);
  const int xcd = flat & 7;
  const int idx = flat >> 3;
  const int bh = xcd * 8 + (idx >> 4);  // 8 (b,h) panels per XCD
  const int qb = idx & 15;
  const int b = bh >> 4;
  const int h = bh & 15;
  const int q0w = qb * 128 + wave * 32;

  const size_t base = (size_t)b * 2048 * 2048;
  const __bf16* Qb = QK + base + h * 64;
  const __bf16* Kb = QK + base + 1024 + h * 64;
  const __bf16* Vtb = Vt + (size_t)(b * 16 + h) * 64 * 2048;  // [d][key]

  __shared__ __bf16 Ks[2][64 * 64];  // [r][ch^ (r&7)] = K[prow(r)][ch]
  __shared__ __bf16 Vs[2][64 * 64];  // [d][ch^ (d&7)] = Vt[d][kv0+ch]

  // Q as B-operand: lane holds Q[q0w+l31][dc*16 + half*8 + j]  (pre-scaled)
  bf16x8 qf[4];
#pragma unroll
  for (int dc = 0; dc < 4; ++dc)
    qf[dc] = *(const bf16x8*)&Qb[(size_t)(q0w + l31) * 2048 + dc * 16 + half * 8];

  f32x16 o[2] = {};
  float lsum = 0.0f;

  // ---- staging geometry: wave w, issue i covers rows w*16+i*8 .. +7 ----
  const int l8 = lane >> 3;   // row within 8-row issue group
  const int cl = lane & 7;    // 16B chunk within row
  // K: dest row r = w*16 + i*8 + l8 ; source row = prow(r) (swap bits 2<->3)
  //    r bits: 0-2 = l8, 3 = i, 4-5 = w  ->  prow = w*16 + (l8&3) + i*4 + (l8>>2)*8
  const int prow0 = wave * 16 + (l8 & 3) + (l8 >> 2) * 8;       // i=0
  const int prow1 = prow0 + 4;                                  // i=1
  // source chunk = cl ^ (r&7) = cl ^ l8 (both K and V: low 3 row bits = l8)
  const int csw = (cl ^ l8) << 3;  // elems
  const __bf16* srcK0 = Kb + (size_t)prow0 * 2048 + csw;
  const __bf16* srcK1 = Kb + (size_t)prow1 * 2048 + csw;
  const int d0 = wave * 16 + l8, d1 = d0 + 8;  // V rows (linear)
  const __bf16* srcV0 = Vtb + (size_t)d0 * 2048 + csw;
  const __bf16* srcV1 = Vtb + (size_t)d1 * 2048 + csw;
  const int dstR0 = (wave * 16) * 64;      // elems; DMA adds lane*8
  const int dstR1 = (wave * 16 + 8) * 64;

  // per-lane read swizzle bits
  const int rsw = l31 & 7;

  // ---- prologue: stage tile 0 into buf 0 ----
  gload_lds16(srcK0, &Ks[0][dstR0]);
  gload_lds16(srcK1, &Ks[0][dstR1]);
  gload_lds16(srcV0, &Vs[0][dstR0]);
  gload_lds16(srcV1, &Vs[0][dstR1]);
  asm volatile("s_waitcnt vmcnt(0)" ::: "memory");
  __builtin_amdgcn_sched_barrier(0);
  __syncthreads();

#pragma unroll 2
  for (int it = 0; it < 32; ++it) {
    const int cur = it & 1;

    // ---- issue tile it+1 into the other buffer (overlaps compute) ----
    if (it < 31) {
      const size_t ko = (size_t)(it + 1) * 64 * 2048;
      const int vo = (it + 1) * 64;
      gload_lds16(srcK0 + ko, &Ks[cur ^ 1][dstR0]);
      gload_lds16(srcK1 + ko, &Ks[cur ^ 1][dstR1]);
      gload_lds16(srcV0 + vo, &Vs[cur ^ 1][dstR0]);
      gload_lds16(srcV1 + vo, &Vs[cur ^ 1][dstR1]);
    }

    // ---- S^T = K.Q^T per 32-row tile; exp2 directly into A-frag order ----
    bf16x8 pf[4];
#pragma unroll
    for (int kt = 0; kt < 2; ++kt) {
      f32x16 c = {};
#pragma unroll
      for (int dc = 0; dc < 4; ++dc) {
        bf16x8 kf = *(const bf16x8*)&Ks[cur][(kt * 32 + l31) * 64 +
                                           (((dc * 2 + half) ^ rsw) << 3)];
        c = MFMA32(kf, qf[dc], c);
      }
#pragma unroll
      for (int kkl = 0; kkl < 2; ++kkl) {
        bf16x8 f;
#pragma unroll
        for (int j = 0; j < 8; ++j) {
          float e = __builtin_amdgcn_exp2f(c[8 * kkl + 4 * (j >> 2) + (j & 3)]);
          lsum += e;
          f[j] = (__bf16)e;
        }
        pf[kt * 2 + kkl] = f;
      }
    }

    // ---- O += P V ----
#pragma unroll
    for (int dt = 0; dt < 2; ++dt)
#pragma unroll
      for (int kk = 0; kk < 4; ++kk) {
        bf16x8 vf = *(const bf16x8*)&Vs[cur][(dt * 32 + l31) * 64 +
                                            (((kk * 2 + half) ^ rsw) << 3)];
        o[dt] = MFMA32(pf[kk], vf, o[dt]);
      }

    // ---- own loads retired; all waves' tile it+1 resident after barrier ----
    asm volatile("s_waitcnt vmcnt(0)" ::: "memory");
    __builtin_amdgcn_sched_barrier(0);
    __syncthreads();
  }

  // ---- denominator: the two halves partition each q's keys ----
  lsum += __shfl_xor(lsum, 32);
  float inv = 1.0f / lsum;  // valid for q == l31

  float iv[16];
#pragma unroll
  for (int r = 0; r < 16; ++r)
    iv[r] = __shfl(inv, (r & 3) + 8 * (r >> 2) + 4 * half);

  // ---- epilogue: O C-layout col=l31=d(+32dt), row=q regmap ----
#pragma unroll
  for (int dt = 0; dt < 2; ++dt)
#pragma unroll
    for (int r = 0; r < 16; ++r) {
      int qr = (r & 3) + 8 * (r >> 2) + 4 * half;
      Out[(size_t)(b * 2048 + q0w + qr) * 1024 + h * 64 + dt * 32 + l31] =
          o[dt][r] * iv[r];
    }
}

// ---------------------------------------------------------------------------
extern "C" void kernel_launch(void* const* d_in, const int* in_sizes, int n_in,
                              void* d_out, int out_size, void* d_ws, size_t ws_size,
                              hipStream_t stream) {
  const float* x = (const float*)d_in[0];        // [4,2048,1024] fp32
  const float* w = (const float*)d_in[1];        // [1024,3072]  fp32
  float* out = (float*)d_out;                    // [4,2048,1024] fp32

  __bf16* Wt = (__bf16*)d_ws;                    // [3072,1024]   6.29 MB
  __bf16* QK = Wt + (size_t)3072 * 1024;         // [8192,2048]  33.55 MB
  __bf16* Xb = QK + (size_t)8192 * 2048;         // [8192,1024]  16.78 MB
  __bf16* Vtr = Xb + (size_t)8192 * 1024;        // [64,64,2048] 16.78 MB

  convert_x<<<8192, 256, 0, stream>>>(x, Xb);
  transpose_w<<<dim3(48, 16), 256, 0, stream>>>(w, Wt);
  gemm_qkv<<<dim3(24, 64), 256, 0, stream>>>(Xb, Wt, QK, Vtr);
  attn<<<dim3(16, 16, 4), 256, 0, stream>>>(QK, Vtr, out);
}

// Round 13
// 232.174 us; speedup vs baseline: 1.0251x; 1.0251x over previous
//
#include <hip/hip_runtime.h>
#include <hip/hip_bf16.h>
#include <math.h>

typedef __bf16 bf16x2 __attribute__((ext_vector_type(2)));
typedef __bf16 bf16x4 __attribute__((ext_vector_type(4)));
typedef __bf16 bf16x8 __attribute__((ext_vector_type(8)));
typedef float f32x4 __attribute__((ext_vector_type(4)));
typedef float f32x16 __attribute__((ext_vector_type(16)));

#define MFMA16(a, b, c) __builtin_amdgcn_mfma_f32_16x16x32_bf16(a, b, c, 0, 0, 0)
#define MFMA32(a, b, c) __builtin_amdgcn_mfma_f32_32x32x16_bf16(a, b, c, 0, 0, 0)
#define QSCALE 0.1803368801111204f  // 0.125 * log2(e): folded into W's Q-columns

// async global->LDS, 16B/lane, dest = wave-uniform base + lane*16
__device__ __forceinline__ void gload_lds16(const __bf16* g, __bf16* l) {
  __builtin_amdgcn_global_load_lds((const __attribute__((address_space(1))) void*)g,
                                   (__attribute__((address_space(3))) void*)l,
                                   16, 0, 0);
}

// ---------------------------------------------------------------------------
// Kernel 0: convert X fp32 -> bf16
// ---------------------------------------------------------------------------
__global__ __launch_bounds__(256) void convert_x(const float* __restrict__ in,
                                                 __bf16* __restrict__ out) {
  int i = blockIdx.x * 256 + threadIdx.x;
  float4 v = ((const float4*)in)[i];
  bf16x4 o = {(__bf16)v.x, (__bf16)v.y, (__bf16)v.z, (__bf16)v.w};
  *(bf16x4*)&out[i * 4] = o;
}

// ---------------------------------------------------------------------------
// Kernel 1: transpose+convert W fp32 [1024,3072] -> Wt bf16 [3072,1024].
//   Q output-features (bx<16) pre-scaled by 0.125*log2(e).
// ---------------------------------------------------------------------------
__global__ __launch_bounds__(256) void transpose_w(const float* __restrict__ W,
                                                   __bf16* __restrict__ Wt) {
  __shared__ __bf16 tile[64][65];
  const int bx = blockIdx.x;
  const int by = blockIdx.y;
  const int t = threadIdx.x;
  const int lr = t >> 6;
  const int lc = t & 63;
  const float sc = (bx < 16) ? QSCALE : 1.0f;  // block-uniform
#pragma unroll
  for (int i = 0; i < 16; ++i) {
    int r = lr + i * 4;
    tile[r][lc] = (__bf16)(W[(size_t)(by * 64 + r) * 3072 + bx * 64 + lc] * sc);
  }
  __syncthreads();
#pragma unroll
  for (int i = 0; i < 16; ++i) {
    int r = lr + i * 4;
    Wt[(size_t)(bx * 64 + r) * 1024 + by * 64 + lc] = tile[lc][r];
  }
}

// ---------------------------------------------------------------------------
// Kernel 2: QKV = X @ W. R8/R11-verified structure (128x128 tile, BK=32,
//   global_load_lds w=16, 256 thr, 36KB LDS, 4-block TLP) + XCD 4x2 remap.
//   Unchanged from R11.
// ---------------------------------------------------------------------------
__global__ __launch_bounds__(256) void gemm_qkv(const __bf16* __restrict__ X,
                                                const __bf16* __restrict__ Wt,
                                                __bf16* __restrict__ QK,
                                                __bf16* __restrict__ Vt) {
  __shared__ __bf16 As[128 * 32];
  __shared__ __bf16 Bs[128 * 32];
  const int t = threadIdx.x;
  const int lane = t & 63;
  const int wave = t >> 6;
  const int quad = lane >> 4;
  const int l16 = lane & 15;

  // ---- XCD-aware 4x2 tiling remap (T1) ----
  const int flat = blockIdx.x + blockIdx.y * 24;
  const int xcd = flat & 7;
  const int i = flat >> 3;       // 0..191 within XCD
  const int mg = xcd >> 1;       // 4 m-groups
  const int ng = xcd & 1;        // 2 n-groups
  const int nb = i >> 4;         // 0..11, outer (B panel hot across 16 mb)
  const int mb = i & 15;         // 0..15, inner
  const int n0 = (ng * 12 + nb) * 128;
  const int m0 = (mg * 16 + mb) * 128;

  const int wm = (wave & 1) * 64;
  const int wn = (wave >> 1) * 64;

  const __bf16* Ag = &X[(size_t)(m0 + wave * 16 + (lane >> 2)) * 1024 + (lane & 3) * 8];
  const __bf16* Bg = &Wt[(size_t)(n0 + wave * 16 + (lane >> 2)) * 1024 + (lane & 3) * 8];
  __bf16* As0 = &As[wave * 512];
  __bf16* As1 = &As[2048 + wave * 512];
  __bf16* Bs0 = &Bs[wave * 512];
  __bf16* Bs1 = &Bs[2048 + wave * 512];

  f32x4 acc[4][4] = {};

  for (int k0 = 0; k0 < 1024; k0 += 32) {
    gload_lds16(Ag + k0, As0);
    gload_lds16(Ag + (size_t)64 * 1024 + k0, As1);
    gload_lds16(Bg + k0, Bs0);
    gload_lds16(Bg + (size_t)64 * 1024 + k0, Bs1);
    __syncthreads();

    bf16x8 af[4], bf[4];
#pragma unroll
    for (int mi = 0; mi < 4; ++mi)
      af[mi] = *(const bf16x8*)&As[(wm + mi * 16 + l16) * 32 + quad * 8];
#pragma unroll
    for (int ni = 0; ni < 4; ++ni)
      bf[ni] = *(const bf16x8*)&Bs[(wn + ni * 16 + l16) * 32 + quad * 8];
#pragma unroll
    for (int mi = 0; mi < 4; ++mi)
#pragma unroll
      for (int ni = 0; ni < 4; ++ni)
        acc[mi][ni] = MFMA16(af[mi], bf[ni], acc[mi][ni]);
    __syncthreads();
  }

  if (n0 < 2048) {
    // Q/K epilogue: row-major QK, stride 2048
#pragma unroll
    for (int mi = 0; mi < 4; ++mi)
#pragma unroll
      for (int ni = 0; ni < 4; ++ni)
#pragma unroll
        for (int r = 0; r < 4; ++r) {
          int row = m0 + wm + mi * 16 + quad * 4 + r;
          int col = n0 + wn + ni * 16 + l16;
          QK[(size_t)row * 2048 + col] = (__bf16)acc[mi][ni][r];
        }
  } else {
    // V epilogue: fused transpose into Vt[bh][d][key]; 4 consecutive keys
#pragma unroll
    for (int mi = 0; mi < 4; ++mi)
#pragma unroll
      for (int ni = 0; ni < 4; ++ni) {
        int v = n0 + wn + ni * 16 + l16 - 2048;
        int hh = v >> 6, d = v & 63;
        int row0 = m0 + wm + mi * 16 + quad * 4;
        int bb = row0 >> 11, key = row0 & 2047;
        bf16x4 pk = {(__bf16)acc[mi][ni][0], (__bf16)acc[mi][ni][1],
                     (__bf16)acc[mi][ni][2], (__bf16)acc[mi][ni][3]};
        *(bf16x4*)&Vt[((size_t)(bb * 16 + hh) * 64 + d) * 2048 + key] = pk;
      }
  }
}

// ---------------------------------------------------------------------------
// Kernel 3: flash attention, 32x32x16 MFMA, PERMUTED-K staging + T1 remap.
//   Staging/compute body = R8-verified (87.7 us, 0 conflicts; R12's
//   unpadded gload_lds variant gave 8.4M conflicts and NO VALU drop ->
//   reverted).
//   NEW: denominator via ONES-MFMA instead of 32 serial VALU adds.
//     ssum = MFMA32(pf[kk], ones, ssum): D[q][j] = Sum_key P[q][key] for
//     every col j. C-layout row = (r&3)+8*(r>>2)+4*half = the SAME q the
//     epilogue divides at reg r -> iv[r] = 1/ssum[r]; no lsum chain, no
//     shfl_xor (MFMA reduces the full K dim incl. both halves), no shfl
//     broadcast loop. Shifts ~64-128 cyc/round off the 55%-busy VALU pipe
//     onto the 35%-busy MFMA pipe (+4 MFMA32/round).
// ---------------------------------------------------------------------------
#define AT_LD 72  // 144B rows, 16B-aligned

__global__ __launch_bounds__(256) void attn(const __bf16* __restrict__ QK,
                                            const __bf16* __restrict__ Vt,
                                            float* __restrict__ Out) {
  const int t = threadIdx.x;
  const int lane = t & 63;
  const int wave = t >> 6;
  const int l31 = lane & 31;
  const int half = lane >> 5;

  // ---- XCD-aware remap (T1) ----
  const int flat = blockIdx.x + (blockIdx.y << 4) + (blockIdx.z << 8);
  const int xcd = flat & 7;
  const int idx = flat >> 3;
  const int bh = xcd * 8 + (idx >> 4);  // 8 (b,h) panels per XCD
  const int qb = idx & 15;
  const int b = bh >> 4;
  const int h = bh & 15;
  const int q0w = qb * 128 + wave * 32;

  const size_t base = (size_t)b * 2048 * 2048;
  const __bf16* Qb = QK + base + h * 64;
  const __bf16* Kb = QK + base + 1024 + h * 64;
  const __bf16* Vtb = Vt + (size_t)(b * 16 + h) * 64 * 2048;  // [d][key]

  __shared__ __bf16 Ks[64 * AT_LD];  // [perm(key)][d]
  __shared__ __bf16 Vs[64 * AT_LD];  // [d][key]

  // Q as B-operand: lane holds Q[q0w+l31][dc*16 + half*8 + j]  (pre-scaled)
  bf16x8 qf[4];
#pragma unroll
  for (int dc = 0; dc < 4; ++dc)
    qf[dc] = *(const bf16x8*)&Qb[(size_t)(q0w + l31) * 2048 + dc * 16 + half * 8];

  f32x16 o[2] = {};
  f32x16 ssum = {};  // denominator via ones-MFMA (row q = epilogue regmap)
  bf16x8 onesb;
#pragma unroll
  for (int j = 0; j < 8; ++j) onesb[j] = (__bf16)1.0f;

  const int srow = t >> 2;      // staging row 0..63
  const int sc = (t & 3) * 16;  // staging col chunk
  // K dest row: swap bits 2<->3 (involution); bits 0,1,4,5 kept
  const int prow = (srow & 51) | ((srow & 4) << 1) | ((srow & 8) >> 1);

  for (int kv0 = 0; kv0 < 2048; kv0 += 64) {
    // ---- stage K (row-permuted) and V ----
    bf16x8 k0v = *(const bf16x8*)&Kb[(size_t)(kv0 + srow) * 2048 + sc];
    bf16x8 k1v = *(const bf16x8*)&Kb[(size_t)(kv0 + srow) * 2048 + sc + 8];
    bf16x8 v0v = *(const bf16x8*)&Vtb[(size_t)srow * 2048 + kv0 + sc];
    bf16x8 v1v = *(const bf16x8*)&Vtb[(size_t)srow * 2048 + kv0 + sc + 8];
    __syncthreads();
    *(bf16x8*)&Ks[prow * AT_LD + sc] = k0v;
    *(bf16x8*)&Ks[prow * AT_LD + sc + 8] = k1v;
    *(bf16x8*)&Vs[srow * AT_LD + sc] = v0v;
    *(bf16x8*)&Vs[srow * AT_LD + sc + 8] = v1v;
    __syncthreads();

    // ---- S^T = K.Q^T per 32-row tile; exp2 directly into A-frag order ----
    bf16x8 pf[4];
#pragma unroll
    for (int kt = 0; kt < 2; ++kt) {
      f32x16 c = {};
#pragma unroll
      for (int dc = 0; dc < 4; ++dc) {
        bf16x8 kf = *(const bf16x8*)&Ks[(kt * 32 + l31) * AT_LD + dc * 16 + half * 8];
        c = MFMA32(kf, qf[dc], c);
      }
#pragma unroll
      for (int kkl = 0; kkl < 2; ++kkl) {
        bf16x8 f;
#pragma unroll
        for (int j = 0; j < 8; ++j) {
          float e = __builtin_amdgcn_exp2f(c[8 * kkl + 4 * (j >> 2) + (j & 3)]);
          f[j] = (__bf16)e;
        }
        pf[kt * 2 + kkl] = f;
      }
    }

    // ---- O += P V ; denominator += P . ones (MFMA pipe) ----
#pragma unroll
    for (int kk = 0; kk < 4; ++kk) {
      bf16x8 vf0 = *(const bf16x8*)&Vs[(l31)*AT_LD + kk * 16 + half * 8];
      bf16x8 vf1 = *(const bf16x8*)&Vs[(32 + l31) * AT_LD + kk * 16 + half * 8];
      o[0] = MFMA32(pf[kk], vf0, o[0]);
      o[1] = MFMA32(pf[kk], vf1, o[1]);
      ssum = MFMA32(pf[kk], onesb, ssum);
    }
  }

  // ---- epilogue: O C-layout col=l31=d(+32dt), row=q regmap; ssum[r] is
  //      the denominator for exactly that q -> no cross-lane ops ----
  float iv[16];
#pragma unroll
  for (int r = 0; r < 16; ++r)
    iv[r] = 1.0f / ssum[r];

#pragma unroll
  for (int dt = 0; dt < 2; ++dt)
#pragma unroll
    for (int r = 0; r < 16; ++r) {
      int qr = (r & 3) + 8 * (r >> 2) + 4 * half;
      Out[(size_t)(b * 2048 + q0w + qr) * 1024 + h * 64 + dt * 32 + l31] =
          o[dt][r] * iv[r];
    }
}

// ---------------------------------------------------------------------------
extern "C" void kernel_launch(void* const* d_in, const int* in_sizes, int n_in,
                              void* d_out, int out_size, void* d_ws, size_t ws_size,
                              hipStream_t stream) {
  const float* x = (const float*)d_in[0];        // [4,2048,1024] fp32
  const float* w = (const float*)d_in[1];        // [1024,3072]  fp32
  float* out = (float*)d_out;                    // [4,2048,1024] fp32

  __bf16* Wt = (__bf16*)d_ws;                    // [3072,1024]   6.29 MB
  __bf16* QK = Wt + (size_t)3072 * 1024;         // [8192,2048]  33.55 MB
  __bf16* Xb = QK + (size_t)8192 * 2048;         // [8192,1024]  16.78 MB
  __bf16* Vtr = Xb + (size_t)8192 * 1024;        // [64,64,2048] 16.78 MB

  convert_x<<<8192, 256, 0, stream>>>(x, Xb);
  transpose_w<<<dim3(48, 16), 256, 0, stream>>>(w, Wt);
  gemm_qkv<<<dim3(24, 64), 256, 0, stream>>>(Xb, Wt, QK, Vtr);
  attn<<<dim3(16, 16, 4), 256, 0, stream>>>(QK, Vtr, out);
}